// Round 12
// baseline (107.041 us; speedup 1.0000x reference)
//
#include <hip/hip_runtime.h>
#include <hip/hip_fp16.h>
#include <math.h>

#define N_HEADS 8
#define N_LEVELS 4
#define N_POINTS 4
#define LQ 5440
#define LV 5440
#define BATCH_ 4
#define M_TOT (BATCH_ * LQ)   // 21760

typedef __bf16 bf16x8 __attribute__((ext_vector_type(8)));
typedef float f32x4 __attribute__((ext_vector_type(4)));
typedef unsigned int uint_t;

__device__ __forceinline__ unsigned short rne_bf16(float x) {
  uint_t u = __float_as_uint(x);
  uint_t r = u + 0x7fffu + ((u >> 16) & 1u);
  return (unsigned short)(r >> 16);
}
__device__ __forceinline__ float bf16_to_f(unsigned short h) {
  return __uint_as_float(((uint_t)h) << 16);
}
__device__ __forceinline__ uint_t f2h2(float a, float b) {   // pack 2 f32 -> half2 (RNE)
  const unsigned short ua = __half_as_ushort(__float2half(a));
  const unsigned short ub = __half_as_ushort(__float2half(b));
  return (uint_t)ua | ((uint_t)ub << 16);
}
__device__ __forceinline__ float h_lo(uint_t u) {
  return __half2float(__ushort_as_half((unsigned short)(u & 0xffffu)));
}
__device__ __forceinline__ float h_hi(uint_t u) {
  return __half2float(__ushort_as_half((unsigned short)(u >> 16)));
}
// HW packed f32->bf16 (RNE): D.lo = bf16(S0), D.hi = bf16(S1)
__device__ __forceinline__ uint_t cvt_pk_bf16(float a, float b) {
  uint_t r;
  asm("v_cvt_pk_bf16_f32 %0, %1, %2" : "=v"(r) : "v"(a), "v"(b));
  return r;
}

// ---------------- input conversion: query -> Q3 (hi|lo), input_flatten -> IFh ----------------
__global__ __launch_bounds__(256) void conv_inputs(
    const float* __restrict__ q, const float* __restrict__ iff,
    unsigned short* __restrict__ Q3, unsigned short* __restrict__ IFh)
{
  const int t = blockIdx.x * 256 + threadIdx.x;   // 0 .. M*64
  const int r = t >> 6;
  const int c = (t & 63) * 4;
  const float4 qa = *(const float4*)(q + (size_t)r * 256 + c);
  ushort4 h, l;
  {
    const float v[4] = {qa.x, qa.y, qa.z, qa.w};
    unsigned short hh[4], ll[4];
#pragma unroll
    for (int i = 0; i < 4; ++i) {
      hh[i] = rne_bf16(v[i]);
      ll[i] = rne_bf16(v[i] - bf16_to_f(hh[i]));
    }
    h = make_ushort4(hh[0], hh[1], hh[2], hh[3]);
    l = make_ushort4(ll[0], ll[1], ll[2], ll[3]);
  }
  *(ushort4*)(Q3 + (size_t)r * 512 + c) = h;
  *(ushort4*)(Q3 + (size_t)r * 512 + 256 + c) = l;
  const float4 fa = *(const float4*)(iff + (size_t)r * 256 + c);
  *(ushort4*)(IFh + (size_t)r * 256 + c) =
      make_ushort4(rne_bf16(fa.x), rne_bf16(fa.y), rne_bf16(fa.z), rne_bf16(fa.w));
}

// ---------------- weight conversion (transpose + bf16) ----------------
// mode 1 (2-term split): W[n][0..255]=hi, [256..511]=hi  (pairs with A=[hi|lo])
// mode 0: Wt[n][0..255]=hi
// Wcat: rows 0..255 = w_off, rows 256..383 = w_attn (both mode 1)
__global__ __launch_bounds__(256) void conv_weights(
    const float* __restrict__ w_off, const float* __restrict__ w_out,
    const float* __restrict__ w_val, const float* __restrict__ w_attn,
    unsigned short* __restrict__ Wcat, unsigned short* __restrict__ Wo2,
    unsigned short* __restrict__ Wvt)
{
  __shared__ float tbuf[64][65];
  const int tid = threadIdx.x;
  const int k0 = blockIdx.x * 64;
  const int yy = blockIdx.y;
  const float* src; unsigned short* dst; int N; int mode; int ntile; int roff = 0;
  if (yy < 4)       { src = w_off;  dst = Wcat; N = 256; mode = 1; ntile = yy; }
  else if (yy < 8)  { src = w_out;  dst = Wo2;  N = 256; mode = 1; ntile = yy - 4; }
  else if (yy < 12) { src = w_val;  dst = Wvt;  N = 256; mode = 0; ntile = yy - 8; }
  else              { src = w_attn; dst = Wcat; N = 128; mode = 1; ntile = yy - 12; roff = 256; }
  const int n0 = ntile * 64;
#pragma unroll
  for (int i = 0; i < 16; ++i) {
    const int r = (tid >> 6) + i * 4;
    const int c = tid & 63;
    tbuf[r][c] = src[(size_t)(k0 + r) * N + n0 + c];
  }
  __syncthreads();
#pragma unroll
  for (int i = 0; i < 16; ++i) {
    const int n = (tid >> 6) + i * 4;
    const int kk = tid & 63;
    const float v = tbuf[kk][n];
    const unsigned short h = rne_bf16(v);
    if (mode) {
      const size_t rowb = (size_t)(roff + n0 + n) * 512;
      dst[rowb + k0 + kk] = h;
      dst[rowb + 256 + k0 + kk] = h;
    } else {
      dst[(size_t)(n0 + n) * 256 + k0 + kk] = h;
    }
  }
}

// ---------------- bf16 MFMA GEMM, m97 structure ----------------
// MODE: 0 = f32 out; 1 = bf16 out;
// 2 = mixed (col<256 -> f16 C1 ldc 256; col>=256 -> bf16 C2 ldc 128)
template<int KSTEPS, int MODE>
__global__ __launch_bounds__(256) void gemm_mfma(
    const unsigned short* __restrict__ A, int lda,
    const unsigned short* __restrict__ Bt,   // [N][KSTEPS*64]
    const float* __restrict__ bias, const float* __restrict__ bias2,
    void* __restrict__ C1, int ldc, void* __restrict__ C2)
{
  constexpr int LDB = KSTEPS * 64;
  __shared__ unsigned short As[128 * 64];
  __shared__ unsigned short Bs[128 * 64];
  const int tid = threadIdx.x;
  const int w = tid >> 6, lane = tid & 63;
  const int wm = w >> 1, wn = w & 1;
  const int lr = lane & 15, lk = lane >> 4;
  const int m0 = blockIdx.y * 128, n0 = blockIdx.x * 128;

  f32x4 acc[4][4] = {};

  for (int t = 0; t < KSTEPS; ++t) {
    const int ka = t * 64;
#pragma unroll
    for (int i = 0; i < 4; ++i) {
      const int rbase = i * 32 + w * 8;
      const int row = rbase + (lane >> 3);
      const int slot = lane & 7;
      const int gs = slot ^ (row & 7);                 // inverse-swizzle the SOURCE (rule 21)
      const unsigned short* gp = A + (size_t)(m0 + row) * lda + ka + gs * 8;
      __builtin_amdgcn_global_load_lds(
          (const __attribute__((address_space(1))) uint_t*)gp,
          (__attribute__((address_space(3))) uint_t*)(As + rbase * 64), 16, 0, 0);
    }
#pragma unroll
    for (int i = 0; i < 4; ++i) {
      const int rbase = i * 32 + w * 8;
      const int row = rbase + (lane >> 3);
      const int slot = lane & 7;
      const int gs = slot ^ (row & 7);
      const unsigned short* gp = Bt + (size_t)(n0 + row) * LDB + ka + gs * 8;
      __builtin_amdgcn_global_load_lds(
          (const __attribute__((address_space(1))) uint_t*)gp,
          (__attribute__((address_space(3))) uint_t*)(Bs + rbase * 64), 16, 0, 0);
    }
    asm volatile("s_waitcnt vmcnt(0)" ::: "memory");
    __syncthreads();
#pragma unroll
    for (int kk = 0; kk < 2; ++kk) {
      bf16x8 af[4], bfv[4];
#pragma unroll
      for (int m = 0; m < 4; ++m) {
        const int row = wm * 64 + m * 16 + lr;
        const int so = (kk * 4 + lk) ^ (row & 7);      // swizzled read
        af[m] = *(const bf16x8*)((const char*)As + row * 128 + so * 16);
      }
#pragma unroll
      for (int n = 0; n < 4; ++n) {
        const int row = wn * 64 + n * 16 + lr;
        const int so = (kk * 4 + lk) ^ (row & 7);
        bfv[n] = *(const bf16x8*)((const char*)Bs + row * 128 + so * 16);
      }
#pragma unroll
      for (int m = 0; m < 4; ++m)
#pragma unroll
        for (int n = 0; n < 4; ++n)
          acc[m][n] = __builtin_amdgcn_mfma_f32_16x16x32_bf16(af[m], bfv[n], acc[m][n], 0, 0, 0);
    }
    __syncthreads();
  }
#pragma unroll
  for (int n = 0; n < 4; ++n) {
    const int col = n0 + wn * 64 + n * 16 + lr;
    const float bv = (MODE == 2 && col >= 256) ? bias2[col - 256] : bias[col];
#pragma unroll
    for (int m = 0; m < 4; ++m) {
      const int rbase = m0 + wm * 64 + m * 16 + lk * 4;
#pragma unroll
      for (int j = 0; j < 4; ++j) {
        const float v = acc[m][n][j] + bv;
        const int row = rbase + j;
        if (MODE == 0) {
          ((float*)C1)[(size_t)row * ldc + col] = v;
        } else if (MODE == 1) {
          ((unsigned short*)C1)[(size_t)row * ldc + col] = rne_bf16(v);
        } else {
          if (col < 256) ((unsigned short*)C1)[(size_t)row * 256 + col] =
              __half_as_ushort(__float2half(v));                 // offsets as f16
          else           ((unsigned short*)C2)[(size_t)row * 128 + (col - 256)] = rne_bf16(v);
        }
      }
    }
  }
}

// ---------------- sampler v12: v10 low-VGPR structure + batch->XCD swizzle + f16 offsets ----
// v10 proved VGPR 28 / occupancy 59% (cvt_pk epilogue, split phase-1); its regression was
// L2 thrash (working set 11.1MB/XCD). v11's swizzle shrinks it to 2.79MB (<4MB L2/XCD).
// Combined: high occupancy hides L2-hit latency with no thrash.
// L = ((P&7)>>1)*680 + (P&1)*340 + (P>>3), bijective for P in [0,2720): batch b -> XCDs {2b,2b+1}.
__global__ __launch_bounds__(256) void msda_sample_v12(
    const unsigned short* __restrict__ off_buf,   // [M,256] f16
    const unsigned short* __restrict__ logit_buf, // [M,128] bf16
    const unsigned short* __restrict__ value,     // [B,LV,256] bf16
    const float* __restrict__ ref_pts,            // [B,LQ,4,2]
    const int*  __restrict__ sshapes, const int* __restrict__ lstart,
    unsigned short* __restrict__ samp3)           // [M,512]
{
  __shared__ uint_t wlds[64 * 68];                // 17,408 B
  const int tid = threadIdx.x;
  const int P  = blockIdx.x;
  const int L  = (((P & 7) >> 1) * 680) + ((P & 1) * 340) + (P >> 3);
  const int q0 = L * 8;
  const int b  = L / (LQ / 8);
  const int q  = tid >> 5;
  const int qg = q0 + q;

  // ---------- phase 1: lane = (q, h, l) ----------
  {
    const int h  = (tid >> 2) & 7;
    const int l  = tid & 3;
    const int Hl = sshapes[2 * l], Wl = sshapes[2 * l + 1];
    const int st = lstart[l];
    const float rx = ref_pts[(size_t)qg * 8 + l * 2 + 0];
    const float ry = ref_pts[(size_t)qg * 8 + l * 2 + 1];
    const float fx = rx * (float)Wl - 0.5f;
    const float fy = ry * (float)Hl - 0.5f;

    // 8 f16 offsets for this (h,l): one uint4; component p = (x_p, y_p)
    const uint4 og = *(const uint4*)(off_buf + (size_t)qg * 256 + h * 32 + l * 8);

    const uint2 lgu = *(const uint2*)(logit_buf + (size_t)qg * 128 + h * 16 + l * 4);
    float lg0 = __uint_as_float(lgu.x << 16);
    float lg1 = __uint_as_float(lgu.x & 0xffff0000u);
    float lg2 = __uint_as_float(lgu.y << 16);
    float lg3 = __uint_as_float(lgu.y & 0xffff0000u);

    // cooperative softmax over the 16 logits of (q,h) (4 lanes x 4)
    float mx = fmaxf(fmaxf(lg0, lg1), fmaxf(lg2, lg3));
    mx = fmaxf(mx, __shfl_xor(mx, 1));
    mx = fmaxf(mx, __shfl_xor(mx, 2));
    float ex[4];
    ex[0] = __expf(lg0 - mx); ex[1] = __expf(lg1 - mx);
    ex[2] = __expf(lg2 - mx); ex[3] = __expf(lg3 - mx);
    float ssum = ex[0] + ex[1] + ex[2] + ex[3];
    ssum += __shfl_xor(ssum, 1);
    ssum += __shfl_xor(ssum, 2);
    const float inv = 1.f / ssum;

    const uint_t base_idx = (uint_t)b * LV + (uint_t)st;   // absolute element-row base
    uint_t* wrow = wlds + (size_t)(q * 8 + h) * 68;
    const uint_t ogc[4] = {og.x, og.y, og.z, og.w};

#pragma unroll
    for (int p = 0; p < 4; ++p) {
      const float x = fx + h_lo(ogc[p]);
      const float y = fy + h_hi(ogc[p]);
      const float aw = ex[p] * inv;
      const float xf = floorf(x), yf = floorf(y);
      const int x0i = (int)xf, y0i = (int)yf;
      const float wx1 = x - xf, wy1 = y - yf;
      const float wx0 = 1.f - wx1, wy0 = 1.f - wy1;
      const int x1i = x0i + 1, y1i = y0i + 1;
      const bool vx0 = (uint_t)x0i < (uint_t)Wl, vx1 = (uint_t)x1i < (uint_t)Wl;
      const bool vy0 = (uint_t)y0i < (uint_t)Hl, vy1 = (uint_t)y1i < (uint_t)Hl;
      const int xc0 = min(max(x0i, 0), Wl - 1), xc1 = min(max(x1i, 0), Wl - 1);
      const int yc0 = min(max(y0i, 0), Hl - 1), yc1 = min(max(y1i, 0), Hl - 1);
      const float awy0 = aw * wy0, awy1 = aw * wy1;
      const float w00 = (vy0 && vx0) ? awy0 * wx0 : 0.f;
      const float w01 = (vy0 && vx1) ? awy0 * wx1 : 0.f;
      const float w10 = (vy1 && vx0) ? awy1 * wx0 : 0.f;
      const float w11 = (vy1 && vx1) ? awy1 * wx1 : 0.f;
      const uint_t r0 = base_idx + (uint_t)(yc0 * Wl), r1 = base_idx + (uint_t)(yc1 * Wl);
      uint4 pk;
      pk.x = f2h2(w00, w01);
      pk.y = f2h2(w10, w11);
      pk.z = (r0 + (uint_t)xc0) | ((r0 + (uint_t)xc1) << 16);
      pk.w = (r1 + (uint_t)xc0) | ((r1 + (uint_t)xc1) << 16);
      *(uint4*)(wrow + (l * 4 + p) * 4) = pk;
    }
  }
  __syncthreads();

  // ---------- phase 2: lane = (q, h, dg) ----------
  const int h  = (tid >> 2) & 7;
  const int dg = tid & 3;
  const uint_t* wrow = wlds + (size_t)(q * 8 + h) * 68;
  const char* vbyte = (const char*)value + (uint_t)h * 64u + (uint_t)dg * 16u;
  float acc[8] = {};

#define ACCUM8V(U4, WV) {                                                          \
    const uint_t uu0 = (U4).x, uu1 = (U4).y, uu2 = (U4).z, uu3 = (U4).w;           \
    acc[0] = fmaf((WV), __uint_as_float(uu0 << 16),         acc[0]);               \
    acc[1] = fmaf((WV), __uint_as_float(uu0 & 0xffff0000u), acc[1]);               \
    acc[2] = fmaf((WV), __uint_as_float(uu1 << 16),         acc[2]);               \
    acc[3] = fmaf((WV), __uint_as_float(uu1 & 0xffff0000u), acc[3]);               \
    acc[4] = fmaf((WV), __uint_as_float(uu2 << 16),         acc[4]);               \
    acc[5] = fmaf((WV), __uint_as_float(uu2 & 0xffff0000u), acc[5]);               \
    acc[6] = fmaf((WV), __uint_as_float(uu3 << 16),         acc[6]);               \
    acc[7] = fmaf((WV), __uint_as_float(uu3 & 0xffff0000u), acc[7]); }

#pragma unroll
  for (int pt = 0; pt < 16; ++pt) {
    const uint4 pk = *(const uint4*)(wrow + pt * 4);
    const float w0 = h_lo(pk.x), w1 = h_hi(pk.x);
    const float w2 = h_lo(pk.y), w3 = h_hi(pk.y);
    const uint_t i0 = pk.z & 0xffffu, i1 = pk.z >> 16;
    const uint_t i2 = pk.w & 0xffffu, i3 = pk.w >> 16;
    { const uint4 g = *(const uint4*)(vbyte + (size_t)i0 * 512u); ACCUM8V(g, w0); }
    { const uint4 g = *(const uint4*)(vbyte + (size_t)i1 * 512u); ACCUM8V(g, w1); }
    { const uint4 g = *(const uint4*)(vbyte + (size_t)i2 * 512u); ACCUM8V(g, w2); }
    { const uint4 g = *(const uint4*)(vbyte + (size_t)i3 * 512u); ACCUM8V(g, w3); }
  }

  // epilogue: packed bf16 hi|lo via v_cvt_pk_bf16_f32 (RNE), two 16B stores
  uint_t hp[4], lp[4];
#pragma unroll
  for (int i = 0; i < 4; ++i) {
    hp[i] = cvt_pk_bf16(acc[2 * i], acc[2 * i + 1]);
    const float lo0 = acc[2 * i]     - __uint_as_float(hp[i] << 16);
    const float lo1 = acc[2 * i + 1] - __uint_as_float(hp[i] & 0xffff0000u);
    lp[i] = cvt_pk_bf16(lo0, lo1);
  }
  unsigned short* op = samp3 + (size_t)qg * 512 + h * 32 + dg * 8;
  *(uint4*)(op)       = make_uint4(hp[0], hp[1], hp[2], hp[3]);
  *(uint4*)(op + 256) = make_uint4(lp[0], lp[1], lp[2], lp[3]);
}

extern "C" void kernel_launch(void* const* d_in, const int* in_sizes, int n_in,
                              void* d_out, int out_size, void* d_ws, size_t ws_size,
                              hipStream_t stream) {
  const float* query         = (const float*)d_in[0];
  const float* ref_pts       = (const float*)d_in[1];
  const float* input_flatten = (const float*)d_in[2];
  const int*   sshapes       = (const int*)d_in[3];
  const int*   lstart        = (const int*)d_in[4];
  const float* w_val  = (const float*)d_in[5];
  const float* b_val  = (const float*)d_in[6];
  const float* w_off  = (const float*)d_in[7];
  const float* b_off  = (const float*)d_in[8];
  const float* w_attn = (const float*)d_in[9];
  const float* b_attn = (const float*)d_in[10];
  const float* w_out  = (const float*)d_in[11];
  const float* b_out  = (const float*)d_in[12];
  float* out = (float*)d_out;

  char* ws = (char*)d_ws;
  unsigned short* Q3     = (unsigned short*)(ws);                 // 22,282,240 B (reused as samp3)
  unsigned short* IFh    = (unsigned short*)(ws + 22282240);      // 11,141,120
  unsigned short* valb   = (unsigned short*)(ws + 33423360);      // 11,141,120
  unsigned short* offb   = (unsigned short*)(ws + 44564480);      // 11,141,120  [M,256] f16
  unsigned short* logitb = (unsigned short*)(ws + 55705600);      //  5,570,560
  unsigned short* Wcat   = (unsigned short*)(ws + 61276160);      //    393,216  [384][512]
  unsigned short* Wo2    = (unsigned short*)(ws + 61669376);      //    262,144  [256][512]
  unsigned short* Wvt    = (unsigned short*)(ws + 61931520);      //    131,072  [256][256]
  unsigned short* samp3  = Q3;  // Q3 dead after the fused off/logit GEMM

  dim3 blk(256);
  conv_inputs<<<dim3(M_TOT / 4), blk, 0, stream>>>(query, input_flatten, Q3, IFh);
  conv_weights<<<dim3(4, 14), blk, 0, stream>>>(w_off, w_out, w_val, w_attn, Wcat, Wo2, Wvt);
  // value = IFh @ w_val (plain bf16), out bf16
  gemm_mfma<4, 1><<<dim3(2, M_TOT / 128), blk, 0, stream>>>(
      IFh, 256, Wvt, b_val, nullptr, (void*)valb, 256, nullptr);
  // fused: [off | logits] = [Q_hi|Q_lo] @ Wcat^T, K=512, mixed epilogue (off as f16)
  gemm_mfma<8, 2><<<dim3(3, M_TOT / 128), blk, 0, stream>>>(
      Q3, 512, Wcat, b_off, b_attn, (void*)offb, 256, (void*)logitb);
  msda_sample_v12<<<dim3(M_TOT / 8), blk, 0, stream>>>(
      offb, logitb, valb, ref_pts, sshapes, lstart, samp3);
  // out = [samp_hi|samp_lo] @ [Wo_hi|Wo_hi], K=512, out f32
  gemm_mfma<8, 0><<<dim3(2, M_TOT / 128), blk, 0, stream>>>(
      samp3, 512, Wo2, b_out, nullptr, (void*)out, 256, nullptr);
}

// Round 13
// 97.145 us; speedup vs baseline: 1.1019x; 1.1019x over previous
//
#include <hip/hip_runtime.h>
#include <hip/hip_fp16.h>
#include <math.h>

#define N_HEADS 8
#define N_LEVELS 4
#define N_POINTS 4
#define LQ 5440
#define LV 5440
#define BATCH_ 4
#define M_TOT (BATCH_ * LQ)   // 21760

typedef __bf16 bf16x8 __attribute__((ext_vector_type(8)));
typedef float f32x4 __attribute__((ext_vector_type(4)));
typedef unsigned int uint_t;

__device__ __forceinline__ unsigned short rne_bf16(float x) {
  uint_t u = __float_as_uint(x);
  uint_t r = u + 0x7fffu + ((u >> 16) & 1u);
  return (unsigned short)(r >> 16);
}
__device__ __forceinline__ float bf16_to_f(unsigned short h) {
  return __uint_as_float(((uint_t)h) << 16);
}
__device__ __forceinline__ uint_t f2h2(float a, float b) {   // pack 2 f32 -> half2 (RNE)
  const unsigned short ua = __half_as_ushort(__float2half(a));
  const unsigned short ub = __half_as_ushort(__float2half(b));
  return (uint_t)ua | ((uint_t)ub << 16);
}
__device__ __forceinline__ float h_lo(uint_t u) {
  return __half2float(__ushort_as_half((unsigned short)(u & 0xffffu)));
}
__device__ __forceinline__ float h_hi(uint_t u) {
  return __half2float(__ushort_as_half((unsigned short)(u >> 16)));
}
// HW packed f32->bf16 (RNE): D.lo = bf16(S0), D.hi = bf16(S1)
__device__ __forceinline__ uint_t cvt_pk_bf16(float a, float b) {
  uint_t r;
  asm("v_cvt_pk_bf16_f32 %0, %1, %2" : "=v"(r) : "v"(a), "v"(b));
  return r;
}

// ---------------- weight conversion (transpose + bf16) ----------------
// Wcat [384][256]: rows 0..255 = w_off^T hi, rows 256..383 = w_attn^T hi
// Wo2  [256][512]: w_out^T hi duplicated (hi|hi) -- pairs with samp3=[hi|lo]
// Wvt  [256][256]: w_val^T hi
__global__ __launch_bounds__(256) void conv_weights(
    const float* __restrict__ w_off, const float* __restrict__ w_out,
    const float* __restrict__ w_val, const float* __restrict__ w_attn,
    unsigned short* __restrict__ Wcat, unsigned short* __restrict__ Wo2,
    unsigned short* __restrict__ Wvt)
{
  __shared__ float tbuf[64][65];
  const int tid = threadIdx.x;
  const int k0 = blockIdx.x * 64;
  const int yy = blockIdx.y;
  const float* src; unsigned short* dst; int N; int dup; int ntile; int roff = 0;
  if (yy < 4)       { src = w_off;  dst = Wcat; N = 256; dup = 0; ntile = yy; }
  else if (yy < 8)  { src = w_out;  dst = Wo2;  N = 256; dup = 1; ntile = yy - 4; }
  else if (yy < 12) { src = w_val;  dst = Wvt;  N = 256; dup = 0; ntile = yy - 8; }
  else              { src = w_attn; dst = Wcat; N = 128; dup = 0; ntile = yy - 12; roff = 256; }
  const int n0 = ntile * 64;
#pragma unroll
  for (int i = 0; i < 16; ++i) {
    const int r = (tid >> 6) + i * 4;
    const int c = tid & 63;
    tbuf[r][c] = src[(size_t)(k0 + r) * N + n0 + c];
  }
  __syncthreads();
#pragma unroll
  for (int i = 0; i < 16; ++i) {
    const int n = (tid >> 6) + i * 4;
    const int kk = tid & 63;
    const float v = tbuf[kk][n];
    const unsigned short h = rne_bf16(v);
    if (dup) {
      const size_t rowb = (size_t)(n0 + n) * 512;
      dst[rowb + k0 + kk] = h;
      dst[rowb + 256 + k0 + kk] = h;
    } else {
      dst[(size_t)(roff + n0 + n) * 256 + k0 + kk] = h;
    }
  }
}

// ---------------- bf16 MFMA GEMM, m97 structure ----------------
// MODE: 0 = f32 out; 1 = bf16 out;
// 2 = mixed (col<256 -> f16 C1 ldc 256; col>=256 -> bf16 C2 ldc 128)
// ASRC: 0 = A bf16 (global_load_lds); 1 = A f32 -> bf16 hi (reg-staged cvt_pk, single read)
template<int KSTEPS, int MODE, int ASRC>
__global__ __launch_bounds__(256) void gemm_mfma(
    const void* __restrict__ Avoid, int lda,
    const unsigned short* __restrict__ Bt,   // [N][KSTEPS*64]
    const float* __restrict__ bias, const float* __restrict__ bias2,
    void* __restrict__ C1, int ldc, void* __restrict__ C2)
{
  constexpr int LDB = KSTEPS * 64;
  __shared__ unsigned short As[128 * 64];
  __shared__ unsigned short Bs[128 * 64];
  const int tid = threadIdx.x;
  const int w = tid >> 6, lane = tid & 63;
  const int wm = w >> 1, wn = w & 1;
  const int lr = lane & 15, lk = lane >> 4;
  const int m0 = blockIdx.y * 128, n0 = blockIdx.x * 128;

  f32x4 acc[4][4] = {};

  for (int t = 0; t < KSTEPS; ++t) {
    const int ka = t * 64;
    // B staging first (async global_load_lds overlaps A's cvt work when ASRC=1)
#pragma unroll
    for (int i = 0; i < 4; ++i) {
      const int rbase = i * 32 + w * 8;
      const int row = rbase + (lane >> 3);
      const int slot = lane & 7;
      const int gs = slot ^ (row & 7);                 // inverse-swizzle the SOURCE (rule 21)
      const unsigned short* gp = Bt + (size_t)(n0 + row) * LDB + ka + gs * 8;
      __builtin_amdgcn_global_load_lds(
          (const __attribute__((address_space(1))) uint_t*)gp,
          (__attribute__((address_space(3))) uint_t*)(Bs + rbase * 64), 16, 0, 0);
    }
    if constexpr (ASRC == 0) {
      const unsigned short* Abf = (const unsigned short*)Avoid;
#pragma unroll
      for (int i = 0; i < 4; ++i) {
        const int rbase = i * 32 + w * 8;
        const int row = rbase + (lane >> 3);
        const int slot = lane & 7;
        const int gs = slot ^ (row & 7);
        const unsigned short* gp = Abf + (size_t)(m0 + row) * lda + ka + gs * 8;
        __builtin_amdgcn_global_load_lds(
            (const __attribute__((address_space(1))) uint_t*)gp,
            (__attribute__((address_space(3))) uint_t*)(As + rbase * 64), 16, 0, 0);
      }
    } else {
      const float* Af = (const float*)Avoid;
#pragma unroll
      for (int i = 0; i < 4; ++i) {
        const int rbase = i * 32 + w * 8;
        const int row = rbase + (lane >> 3);
        const int slot = lane & 7;
        const int gs = slot ^ (row & 7);
        const float* gp = Af + (size_t)(m0 + row) * lda + ka + gs * 8;
        const float4 a0 = *(const float4*)gp;
        const float4 a1 = *(const float4*)(gp + 4);
        const uint_t q0 = cvt_pk_bf16(a0.x, a0.y);
        const uint_t q1 = cvt_pk_bf16(a0.z, a0.w);
        const uint_t q2 = cvt_pk_bf16(a1.x, a1.y);
        const uint_t q3 = cvt_pk_bf16(a1.z, a1.w);
        *(uint4*)&As[(size_t)row * 64 + slot * 8] = make_uint4(q0, q1, q2, q3);
      }
    }
    asm volatile("s_waitcnt vmcnt(0)" ::: "memory");
    __syncthreads();
#pragma unroll
    for (int kk = 0; kk < 2; ++kk) {
      bf16x8 af[4], bfv[4];
#pragma unroll
      for (int m = 0; m < 4; ++m) {
        const int row = wm * 64 + m * 16 + lr;
        const int so = (kk * 4 + lk) ^ (row & 7);      // swizzled read
        af[m] = *(const bf16x8*)((const char*)As + row * 128 + so * 16);
      }
#pragma unroll
      for (int n = 0; n < 4; ++n) {
        const int row = wn * 64 + n * 16 + lr;
        const int so = (kk * 4 + lk) ^ (row & 7);
        bfv[n] = *(const bf16x8*)((const char*)Bs + row * 128 + so * 16);
      }
#pragma unroll
      for (int m = 0; m < 4; ++m)
#pragma unroll
        for (int n = 0; n < 4; ++n)
          acc[m][n] = __builtin_amdgcn_mfma_f32_16x16x32_bf16(af[m], bfv[n], acc[m][n], 0, 0, 0);
    }
    __syncthreads();
  }
#pragma unroll
  for (int n = 0; n < 4; ++n) {
    const int col = n0 + wn * 64 + n * 16 + lr;
    const float bv = (MODE == 2 && col >= 256) ? bias2[col - 256] : bias[col];
#pragma unroll
    for (int m = 0; m < 4; ++m) {
      const int rbase = m0 + wm * 64 + m * 16 + lk * 4;
#pragma unroll
      for (int j = 0; j < 4; ++j) {
        const float v = acc[m][n][j] + bv;
        const int row = rbase + j;
        if (MODE == 0) {
          ((float*)C1)[(size_t)row * ldc + col] = v;
        } else if (MODE == 1) {
          ((unsigned short*)C1)[(size_t)row * ldc + col] = rne_bf16(v);
        } else {
          if (col < 256) ((unsigned short*)C1)[(size_t)row * 256 + col] =
              __half_as_ushort(__float2half(v));                 // offsets as f16
          else           ((unsigned short*)C2)[(size_t)row * 128 + (col - 256)] = rne_bf16(v);
        }
      }
    }
  }
}

// ---------------- sampler v13 == v11 (best: 45.5us): two-phase + batch->XCD swizzle ----------
// Per-XCD value working set 2.79MB (<4MB L2/XCD): gather stream L2-resident.
// L = ((P&7)>>1)*680 + (P&1)*340 + (P>>3), bijective for P in [0,2720): batch b -> XCDs {2b,2b+1}.
__global__ __launch_bounds__(256) void msda_sample_v13(
    const unsigned short* __restrict__ off_buf,   // [M,256] f16
    const unsigned short* __restrict__ logit_buf, // [M,128] bf16
    const unsigned short* __restrict__ value,     // [B,LV,256] bf16
    const float* __restrict__ ref_pts,            // [B,LQ,4,2]
    const int*  __restrict__ sshapes, const int* __restrict__ lstart,
    unsigned short* __restrict__ samp3)           // [M,512]
{
  __shared__ uint_t wlds[64 * 68];                // 17,408 B
  const int tid = threadIdx.x;
  const int P  = blockIdx.x;
  const int L  = (((P & 7) >> 1) * 680) + ((P & 1) * 340) + (P >> 3);
  const int q0 = L * 8;
  const int b  = L / (LQ / 8);
  const int q  = tid >> 5;
  const int qg = q0 + q;

  // ---------- phase 1: lane = (q, h, l) ----------
  {
    const int h  = (tid >> 2) & 7;
    const int l  = tid & 3;
    const int Hl = sshapes[2 * l], Wl = sshapes[2 * l + 1];
    const int st = lstart[l];
    const float rx = ref_pts[(size_t)qg * 8 + l * 2 + 0];
    const float ry = ref_pts[(size_t)qg * 8 + l * 2 + 1];
    const float fx = rx * (float)Wl - 0.5f;
    const float fy = ry * (float)Hl - 0.5f;

    // 8 f16 offsets for this (h,l): one uint4, coalesced
    const uint4 og = *(const uint4*)(off_buf + (size_t)qg * 256 + h * 32 + l * 8);
    const float offv[8] = {h_lo(og.x), h_hi(og.x), h_lo(og.y), h_hi(og.y),
                           h_lo(og.z), h_hi(og.z), h_lo(og.w), h_hi(og.w)};

    const uint2 lgu = *(const uint2*)(logit_buf + (size_t)qg * 128 + h * 16 + l * 4);
    float lg[4];
    lg[0] = __uint_as_float(lgu.x << 16);
    lg[1] = __uint_as_float(lgu.x & 0xffff0000u);
    lg[2] = __uint_as_float(lgu.y << 16);
    lg[3] = __uint_as_float(lgu.y & 0xffff0000u);

    // cooperative softmax over the 16 logits of (q,h) (4 lanes x 4)
    float mx = fmaxf(fmaxf(lg[0], lg[1]), fmaxf(lg[2], lg[3]));
    mx = fmaxf(mx, __shfl_xor(mx, 1));
    mx = fmaxf(mx, __shfl_xor(mx, 2));
    float ex[4]; float ssum = 0.f;
#pragma unroll
    for (int p = 0; p < 4; ++p) { ex[p] = __expf(lg[p] - mx); ssum += ex[p]; }
    ssum += __shfl_xor(ssum, 1);
    ssum += __shfl_xor(ssum, 2);
    const float inv = 1.f / ssum;

    const uint_t base_idx = (uint_t)b * LV + (uint_t)st;   // absolute element-row base
    uint_t* wrow = wlds + (size_t)(q * 8 + h) * 68;

#pragma unroll
    for (int p = 0; p < 4; ++p) {
      const float x = fx + offv[p * 2 + 0];
      const float y = fy + offv[p * 2 + 1];
      const float aw = ex[p] * inv;
      const float xf = floorf(x), yf = floorf(y);
      const int x0i = (int)xf, y0i = (int)yf;
      const float wx1 = x - xf, wy1 = y - yf;
      const float wx0 = 1.f - wx1, wy0 = 1.f - wy1;
      const int x1i = x0i + 1, y1i = y0i + 1;
      const bool vx0 = (uint_t)x0i < (uint_t)Wl, vx1 = (uint_t)x1i < (uint_t)Wl;
      const bool vy0 = (uint_t)y0i < (uint_t)Hl, vy1 = (uint_t)y1i < (uint_t)Hl;
      const int xc0 = min(max(x0i, 0), Wl - 1), xc1 = min(max(x1i, 0), Wl - 1);
      const int yc0 = min(max(y0i, 0), Hl - 1), yc1 = min(max(y1i, 0), Hl - 1);
      const float awy0 = aw * wy0, awy1 = aw * wy1;
      const float w00 = (vy0 && vx0) ? awy0 * wx0 : 0.f;
      const float w01 = (vy0 && vx1) ? awy0 * wx1 : 0.f;
      const float w10 = (vy1 && vx0) ? awy1 * wx0 : 0.f;
      const float w11 = (vy1 && vx1) ? awy1 * wx1 : 0.f;
      const uint_t r0 = base_idx + (uint_t)(yc0 * Wl), r1 = base_idx + (uint_t)(yc1 * Wl);
      uint4 pk;
      pk.x = f2h2(w00, w01);
      pk.y = f2h2(w10, w11);
      pk.z = (r0 + (uint_t)xc0) | ((r0 + (uint_t)xc1) << 16);
      pk.w = (r1 + (uint_t)xc0) | ((r1 + (uint_t)xc1) << 16);
      *(uint4*)(wrow + (l * 4 + p) * 4) = pk;
    }
  }
  __syncthreads();

  // ---------- phase 2: lane = (q, h, dg) ----------
  const int h  = (tid >> 2) & 7;
  const int dg = tid & 3;
  const uint_t* wrow = wlds + (size_t)(q * 8 + h) * 68;
  const char* vbyte = (const char*)value + (uint_t)h * 64u + (uint_t)dg * 16u;
  float acc[8] = {};

#define ACCUM8V(U4, WV) {                                                          \
    const uint_t uu0 = (U4).x, uu1 = (U4).y, uu2 = (U4).z, uu3 = (U4).w;           \
    acc[0] = fmaf((WV), __uint_as_float(uu0 << 16),         acc[0]);               \
    acc[1] = fmaf((WV), __uint_as_float(uu0 & 0xffff0000u), acc[1]);               \
    acc[2] = fmaf((WV), __uint_as_float(uu1 << 16),         acc[2]);               \
    acc[3] = fmaf((WV), __uint_as_float(uu1 & 0xffff0000u), acc[3]);               \
    acc[4] = fmaf((WV), __uint_as_float(uu2 << 16),         acc[4]);               \
    acc[5] = fmaf((WV), __uint_as_float(uu2 & 0xffff0000u), acc[5]);               \
    acc[6] = fmaf((WV), __uint_as_float(uu3 << 16),         acc[6]);               \
    acc[7] = fmaf((WV), __uint_as_float(uu3 & 0xffff0000u), acc[7]); }

#pragma unroll
  for (int pt = 0; pt < 16; ++pt) {
    const uint4 pk = *(const uint4*)(wrow + pt * 4);
    const float w0 = h_lo(pk.x), w1 = h_hi(pk.x);
    const float w2 = h_lo(pk.y), w3 = h_hi(pk.y);
    const uint_t i0 = pk.z & 0xffffu, i1 = pk.z >> 16;
    const uint_t i2 = pk.w & 0xffffu, i3 = pk.w >> 16;
    { const uint4 g = *(const uint4*)(vbyte + (size_t)i0 * 512u); ACCUM8V(g, w0); }
    { const uint4 g = *(const uint4*)(vbyte + (size_t)i1 * 512u); ACCUM8V(g, w1); }
    { const uint4 g = *(const uint4*)(vbyte + (size_t)i2 * 512u); ACCUM8V(g, w2); }
    { const uint4 g = *(const uint4*)(vbyte + (size_t)i3 * 512u); ACCUM8V(g, w3); }
  }

  unsigned short h8[8], l8[8];
#pragma unroll
  for (int i = 0; i < 8; ++i) {
    h8[i] = rne_bf16(acc[i]);
    l8[i] = rne_bf16(acc[i] - bf16_to_f(h8[i]));
  }
  unsigned short* op = samp3 + (size_t)qg * 512 + h * 32 + dg * 8;
  *(ushort4*)(op)       = make_ushort4(h8[0], h8[1], h8[2], h8[3]);
  *(ushort4*)(op + 4)   = make_ushort4(h8[4], h8[5], h8[6], h8[7]);
  *(ushort4*)(op + 256) = make_ushort4(l8[0], l8[1], l8[2], l8[3]);
  *(ushort4*)(op + 260) = make_ushort4(l8[4], l8[5], l8[6], l8[7]);
}

extern "C" void kernel_launch(void* const* d_in, const int* in_sizes, int n_in,
                              void* d_out, int out_size, void* d_ws, size_t ws_size,
                              hipStream_t stream) {
  const float* query         = (const float*)d_in[0];
  const float* ref_pts       = (const float*)d_in[1];
  const float* input_flatten = (const float*)d_in[2];
  const int*   sshapes       = (const int*)d_in[3];
  const int*   lstart        = (const int*)d_in[4];
  const float* w_val  = (const float*)d_in[5];
  const float* b_val  = (const float*)d_in[6];
  const float* w_off  = (const float*)d_in[7];
  const float* b_off  = (const float*)d_in[8];
  const float* w_attn = (const float*)d_in[9];
  const float* b_attn = (const float*)d_in[10];
  const float* w_out  = (const float*)d_in[11];
  const float* b_out  = (const float*)d_in[12];
  float* out = (float*)d_out;

  char* ws = (char*)d_ws;
  unsigned short* valb   = (unsigned short*)(ws);                 // 11,141,120  [B,LV,256] bf16
  unsigned short* samp3  = (unsigned short*)(ws + 11141120);      // 22,282,240  [M,512] hi|lo
  unsigned short* offb   = (unsigned short*)(ws + 33423360);      // 11,141,120  [M,256] f16
  unsigned short* logitb = (unsigned short*)(ws + 44564480);      //  5,570,560  [M,128] bf16
  unsigned short* Wcat   = (unsigned short*)(ws + 50135040);      //    196,608  [384][256]
  unsigned short* Wo2    = (unsigned short*)(ws + 50331648);      //    262,144  [256][512]
  unsigned short* Wvt    = (unsigned short*)(ws + 50593792);      //    131,072  [256][256]

  dim3 blk(256);
  conv_weights<<<dim3(4, 14), blk, 0, stream>>>(w_off, w_out, w_val, w_attn, Wcat, Wo2, Wvt);
  // value = bf16(input_flatten) @ Wvt^T, A reg-staged f32->bf16 in-kernel, out bf16
  gemm_mfma<4, 1, 1><<<dim3(2, M_TOT / 128), blk, 0, stream>>>(
      (const void*)input_flatten, 256, Wvt, b_val, nullptr, (void*)valb, 256, nullptr);
  // fused: [off | logits] = bf16(query) @ Wcat^T, K=256 hi-only, A reg-staged
  gemm_mfma<4, 2, 1><<<dim3(3, M_TOT / 128), blk, 0, stream>>>(
      (const void*)query, 256, Wcat, b_off, b_attn, (void*)offb, 256, (void*)logitb);
  msda_sample_v13<<<dim3(M_TOT / 8), blk, 0, stream>>>(
      offb, logitb, valb, ref_pts, sshapes, lstart, samp3);
  // out = [samp_hi|samp_lo] @ Wo2^T, K=512, A bf16 via global_load_lds
  gemm_mfma<8, 0, 0><<<dim3(2, M_TOT / 128), blk, 0, stream>>>(
      (const void*)samp3, 512, Wo2, b_out, nullptr, (void*)out, 256, nullptr);
}

// Round 15
// 91.278 us; speedup vs baseline: 1.1727x; 1.0643x over previous
//
#include <hip/hip_runtime.h>
#include <hip/hip_fp16.h>
#include <math.h>

#define LQ 5440
#define LV 5440
#define BATCH_ 4
#define M_TOT (BATCH_ * LQ)   // 21760

typedef _Float16 f16x8 __attribute__((ext_vector_type(8)));
typedef float f32x4 __attribute__((ext_vector_type(4)));
typedef unsigned int uint_t;

__device__ __forceinline__ uint_t f2h2(float a, float b) {   // pack 2 f32 -> f16x2 (RNE)
  const unsigned short ua = __half_as_ushort(__float2half(a));
  const unsigned short ub = __half_as_ushort(__float2half(b));
  return (uint_t)ua | ((uint_t)ub << 16);
}
__device__ __forceinline__ uint_t pkrtz(float a, float b) {  // HW packed f32->f16 (RTZ), 1 op
  auto r = __builtin_amdgcn_cvt_pkrtz(a, b);                 // __fp16 ext_vector(2)
  uint_t u;
  __builtin_memcpy(&u, &r, 4);
  return u;
}
__device__ __forceinline__ float h_lo(uint_t u) {
  return __half2float(__ushort_as_half((unsigned short)(u & 0xffffu)));
}
__device__ __forceinline__ float h_hi(uint_t u) {
  return __half2float(__ushort_as_half((unsigned short)(u >> 16)));
}

// ---------------- weight conversion (transpose + f16) ----------------
// Wcat [384][256]: rows 0..255 = w_off^T, rows 256..383 = w_attn^T
// Wo   [256][256]: w_out^T ; Wvt [256][256]: w_val^T   (all f16 RNE)
__global__ __launch_bounds__(256) void conv_weights(
    const float* __restrict__ w_off, const float* __restrict__ w_out,
    const float* __restrict__ w_val, const float* __restrict__ w_attn,
    unsigned short* __restrict__ Wcat, unsigned short* __restrict__ Wo,
    unsigned short* __restrict__ Wvt)
{
  __shared__ float tbuf[64][65];
  const int tid = threadIdx.x;
  const int k0 = blockIdx.x * 64;
  const int yy = blockIdx.y;
  const float* src; unsigned short* dst; int N; int ntile; int roff = 0;
  if (yy < 4)       { src = w_off;  dst = Wcat; N = 256; ntile = yy; }
  else if (yy < 8)  { src = w_out;  dst = Wo;   N = 256; ntile = yy - 4; }
  else if (yy < 12) { src = w_val;  dst = Wvt;  N = 256; ntile = yy - 8; }
  else              { src = w_attn; dst = Wcat; N = 128; ntile = yy - 12; roff = 256; }
  const int n0 = ntile * 64;
#pragma unroll
  for (int i = 0; i < 16; ++i) {
    const int r = (tid >> 6) + i * 4;
    const int c = tid & 63;
    tbuf[r][c] = src[(size_t)(k0 + r) * N + n0 + c];
  }
  __syncthreads();
#pragma unroll
  for (int i = 0; i < 16; ++i) {
    const int n = (tid >> 6) + i * 4;
    const int kk = tid & 63;
    dst[(size_t)(roff + n0 + n) * 256 + k0 + kk] =
        __half_as_ushort(__float2half(tbuf[kk][n]));
  }
}

// ---------------- front GEMM: value + off/logit fused in ONE dispatch ----------------
// grid (5, M/128): xb<2 -> value panel (A=input_flatten, B=Wvt, out valb f16);
// xb in 2..4 -> fused panel (A=query, B=Wcat, out offb f16 / logitb f16).
// K=256; A reg-staged f32 -> f16 (v_cvt_pkrtz) into swizzled LDS; f16 MFMA.
__global__ __launch_bounds__(256) void gemm_front(
    const float* __restrict__ ifl, const float* __restrict__ query,
    const unsigned short* __restrict__ Wvt, const unsigned short* __restrict__ Wcat,
    const float* __restrict__ b_val, const float* __restrict__ b_off,
    const float* __restrict__ b_attn,
    unsigned short* __restrict__ valb, unsigned short* __restrict__ offb,
    unsigned short* __restrict__ logitb)
{
  __shared__ unsigned short As[128 * 64];
  __shared__ unsigned short Bs[128 * 64];
  const int tid = threadIdx.x;
  const int w = tid >> 6, lane = tid & 63;
  const int wm = w >> 1, wn = w & 1;
  const int lr = lane & 15, lk = lane >> 4;
  const int xb = blockIdx.x;
  const bool isval = xb < 2;
  const float* Af = isval ? ifl : query;
  const unsigned short* Bt = isval ? Wvt : Wcat;
  const int n0 = (isval ? xb : xb - 2) * 128;
  const int m0 = blockIdx.y * 128;

  f32x4 acc[4][4] = {};

  for (int t = 0; t < 4; ++t) {
    const int ka = t * 64;
    // B staging (async) first; A cvt work overlaps it
#pragma unroll
    for (int i = 0; i < 4; ++i) {
      const int rbase = i * 32 + w * 8;
      const int row = rbase + (lane >> 3);
      const int slot = lane & 7;
      const int gs = slot ^ (row & 7);                 // inverse-swizzle SOURCE (rule 21)
      const unsigned short* gp = Bt + (size_t)(n0 + row) * 256 + ka + gs * 8;
      __builtin_amdgcn_global_load_lds(
          (const __attribute__((address_space(1))) uint_t*)gp,
          (__attribute__((address_space(3))) uint_t*)(Bs + rbase * 64), 16, 0, 0);
    }
#pragma unroll
    for (int i = 0; i < 4; ++i) {
      const int rbase = i * 32 + w * 8;
      const int row = rbase + (lane >> 3);
      const int slot = lane & 7;
      const int gs = slot ^ (row & 7);
      const float* gp = Af + (size_t)(m0 + row) * 256 + ka + gs * 8;
      const float4 a0 = *(const float4*)gp;
      const float4 a1 = *(const float4*)(gp + 4);
      *(uint4*)&As[(size_t)row * 64 + slot * 8] =
          make_uint4(pkrtz(a0.x, a0.y), pkrtz(a0.z, a0.w),
                     pkrtz(a1.x, a1.y), pkrtz(a1.z, a1.w));
    }
    asm volatile("s_waitcnt vmcnt(0)" ::: "memory");
    __syncthreads();
#pragma unroll
    for (int kk = 0; kk < 2; ++kk) {
      f16x8 af[4], bfv[4];
#pragma unroll
      for (int m = 0; m < 4; ++m) {
        const int row = wm * 64 + m * 16 + lr;
        const int so = (kk * 4 + lk) ^ (row & 7);      // swizzled read
        af[m] = *(const f16x8*)((const char*)As + row * 128 + so * 16);
      }
#pragma unroll
      for (int n = 0; n < 4; ++n) {
        const int row = wn * 64 + n * 16 + lr;
        const int so = (kk * 4 + lk) ^ (row & 7);
        bfv[n] = *(const f16x8*)((const char*)Bs + row * 128 + so * 16);
      }
#pragma unroll
      for (int m = 0; m < 4; ++m)
#pragma unroll
        for (int n = 0; n < 4; ++n)
          acc[m][n] = __builtin_amdgcn_mfma_f32_16x16x32_f16(af[m], bfv[n], acc[m][n], 0, 0, 0);
    }
    __syncthreads();
  }
#pragma unroll
  for (int n = 0; n < 4; ++n) {
    const int col = n0 + wn * 64 + n * 16 + lr;
    const float bv = isval ? b_val[col] : (col < 256 ? b_off[col] : b_attn[col - 256]);
#pragma unroll
    for (int m = 0; m < 4; ++m) {
      const int rbase = m0 + wm * 64 + m * 16 + lk * 4;
#pragma unroll
      for (int j = 0; j < 4; ++j) {
        const float v = acc[m][n][j] + bv;
        const int row = rbase + j;
        const unsigned short hv = __half_as_ushort(__float2half(v));
        if (isval)          valb[(size_t)row * 256 + col] = hv;
        else if (col < 256) offb[(size_t)row * 256 + col] = hv;
        else                logitb[(size_t)row * 128 + (col - 256)] = hv;
      }
    }
  }
}

// ---------------- out GEMM: out = samp(f16) @ Wo^T + b_out, K=256, f32 out ----------------
__global__ __launch_bounds__(256) void gemm_out(
    const unsigned short* __restrict__ A,    // samp f16 [M,256]
    const unsigned short* __restrict__ Bt,   // Wo f16 [256][256]
    const float* __restrict__ bias,
    float* __restrict__ C)
{
  __shared__ unsigned short As[128 * 64];
  __shared__ unsigned short Bs[128 * 64];
  const int tid = threadIdx.x;
  const int w = tid >> 6, lane = tid & 63;
  const int wm = w >> 1, wn = w & 1;
  const int lr = lane & 15, lk = lane >> 4;
  const int m0 = blockIdx.y * 128, n0 = blockIdx.x * 128;

  f32x4 acc[4][4] = {};

  for (int t = 0; t < 4; ++t) {
    const int ka = t * 64;
#pragma unroll
    for (int i = 0; i < 4; ++i) {
      const int rbase = i * 32 + w * 8;
      const int row = rbase + (lane >> 3);
      const int slot = lane & 7;
      const int gs = slot ^ (row & 7);
      const unsigned short* gp = A + (size_t)(m0 + row) * 256 + ka + gs * 8;
      __builtin_amdgcn_global_load_lds(
          (const __attribute__((address_space(1))) uint_t*)gp,
          (__attribute__((address_space(3))) uint_t*)(As + rbase * 64), 16, 0, 0);
    }
#pragma unroll
    for (int i = 0; i < 4; ++i) {
      const int rbase = i * 32 + w * 8;
      const int row = rbase + (lane >> 3);
      const int slot = lane & 7;
      const int gs = slot ^ (row & 7);
      const unsigned short* gp = Bt + (size_t)(n0 + row) * 256 + ka + gs * 8;
      __builtin_amdgcn_global_load_lds(
          (const __attribute__((address_space(1))) uint_t*)gp,
          (__attribute__((address_space(3))) uint_t*)(Bs + rbase * 64), 16, 0, 0);
    }
    asm volatile("s_waitcnt vmcnt(0)" ::: "memory");
    __syncthreads();
#pragma unroll
    for (int kk = 0; kk < 2; ++kk) {
      f16x8 af[4], bfv[4];
#pragma unroll
      for (int m = 0; m < 4; ++m) {
        const int row = wm * 64 + m * 16 + lr;
        const int so = (kk * 4 + lk) ^ (row & 7);
        af[m] = *(const f16x8*)((const char*)As + row * 128 + so * 16);
      }
#pragma unroll
      for (int n = 0; n < 4; ++n) {
        const int row = wn * 64 + n * 16 + lr;
        const int so = (kk * 4 + lk) ^ (row & 7);
        bfv[n] = *(const f16x8*)((const char*)Bs + row * 128 + so * 16);
      }
#pragma unroll
      for (int m = 0; m < 4; ++m)
#pragma unroll
        for (int n = 0; n < 4; ++n)
          acc[m][n] = __builtin_amdgcn_mfma_f32_16x16x32_f16(af[m], bfv[n], acc[m][n], 0, 0, 0);
    }
    __syncthreads();
  }
#pragma unroll
  for (int n = 0; n < 4; ++n) {
    const int col = n0 + wn * 64 + n * 16 + lr;
    const float bv = bias[col];
#pragma unroll
    for (int m = 0; m < 4; ++m) {
      const int rbase = m0 + wm * 64 + m * 16 + lk * 4;
#pragma unroll
      for (int j = 0; j < 4; ++j)
        C[(size_t)(rbase + j) * 256 + col] = acc[m][n][j] + bv;
    }
  }
}

// ---------------- sampler v14: v13 structure (two-phase + batch->XCD swizzle), all-f16 ----
// value [B,LV,256] f16; offsets f16; logits f16; samp out f16 [M,256] single (no hi|lo).
// L = ((P&7)>>1)*680 + (P&1)*340 + (P>>3), bijective for P in [0,2720): batch b -> XCDs {2b,2b+1}.
__global__ __launch_bounds__(256) void msda_sample_v14(
    const unsigned short* __restrict__ off_buf,   // [M,256] f16
    const unsigned short* __restrict__ logit_buf, // [M,128] f16
    const unsigned short* __restrict__ value,     // [B,LV,256] f16
    const float* __restrict__ ref_pts,            // [B,LQ,4,2]
    const int*  __restrict__ sshapes, const int* __restrict__ lstart,
    unsigned short* __restrict__ samp)            // [M,256] f16
{
  __shared__ uint_t wlds[64 * 68];                // 17,408 B
  const int tid = threadIdx.x;
  const int P  = blockIdx.x;
  const int L  = (((P & 7) >> 1) * 680) + ((P & 1) * 340) + (P >> 3);
  const int q0 = L * 8;
  const int b  = L / (LQ / 8);
  const int q  = tid >> 5;
  const int qg = q0 + q;

  // ---------- phase 1: lane = (q, h, l) ----------
  {
    const int h  = (tid >> 2) & 7;
    const int l  = tid & 3;
    const int Hl = sshapes[2 * l], Wl = sshapes[2 * l + 1];
    const int st = lstart[l];
    const float rx = ref_pts[(size_t)qg * 8 + l * 2 + 0];
    const float ry = ref_pts[(size_t)qg * 8 + l * 2 + 1];
    const float fx = rx * (float)Wl - 0.5f;
    const float fy = ry * (float)Hl - 0.5f;

    const uint4 og = *(const uint4*)(off_buf + (size_t)qg * 256 + h * 32 + l * 8);
    const float offv[8] = {h_lo(og.x), h_hi(og.x), h_lo(og.y), h_hi(og.y),
                           h_lo(og.z), h_hi(og.z), h_lo(og.w), h_hi(og.w)};

    const uint2 lgu = *(const uint2*)(logit_buf + (size_t)qg * 128 + h * 16 + l * 4);
    float lg[4];
    lg[0] = h_lo(lgu.x); lg[1] = h_hi(lgu.x);
    lg[2] = h_lo(lgu.y); lg[3] = h_hi(lgu.y);

    // cooperative softmax over the 16 logits of (q,h) (4 lanes x 4)
    float mx = fmaxf(fmaxf(lg[0], lg[1]), fmaxf(lg[2], lg[3]));
    mx = fmaxf(mx, __shfl_xor(mx, 1));
    mx = fmaxf(mx, __shfl_xor(mx, 2));
    float ex[4]; float ssum = 0.f;
#pragma unroll
    for (int p = 0; p < 4; ++p) { ex[p] = __expf(lg[p] - mx); ssum += ex[p]; }
    ssum += __shfl_xor(ssum, 1);
    ssum += __shfl_xor(ssum, 2);
    const float inv = 1.f / ssum;

    const uint_t base_idx = (uint_t)b * LV + (uint_t)st;
    uint_t* wrow = wlds + (size_t)(q * 8 + h) * 68;

#pragma unroll
    for (int p = 0; p < 4; ++p) {
      const float x = fx + offv[p * 2 + 0];
      const float y = fy + offv[p * 2 + 1];
      const float aw = ex[p] * inv;
      const float xf = floorf(x), yf = floorf(y);
      const int x0i = (int)xf, y0i = (int)yf;
      const float wx1 = x - xf, wy1 = y - yf;
      const float wx0 = 1.f - wx1, wy0 = 1.f - wy1;
      const int x1i = x0i + 1, y1i = y0i + 1;
      const bool vx0 = (uint_t)x0i < (uint_t)Wl, vx1 = (uint_t)x1i < (uint_t)Wl;
      const bool vy0 = (uint_t)y0i < (uint_t)Hl, vy1 = (uint_t)y1i < (uint_t)Hl;
      const int xc0 = min(max(x0i, 0), Wl - 1), xc1 = min(max(x1i, 0), Wl - 1);
      const int yc0 = min(max(y0i, 0), Hl - 1), yc1 = min(max(y1i, 0), Hl - 1);
      const float awy0 = aw * wy0, awy1 = aw * wy1;
      const float w00 = (vy0 && vx0) ? awy0 * wx0 : 0.f;
      const float w01 = (vy0 && vx1) ? awy0 * wx1 : 0.f;
      const float w10 = (vy1 && vx0) ? awy1 * wx0 : 0.f;
      const float w11 = (vy1 && vx1) ? awy1 * wx1 : 0.f;
      const uint_t r0 = base_idx + (uint_t)(yc0 * Wl), r1 = base_idx + (uint_t)(yc1 * Wl);
      uint4 pk;
      pk.x = f2h2(w00, w01);
      pk.y = f2h2(w10, w11);
      pk.z = (r0 + (uint_t)xc0) | ((r0 + (uint_t)xc1) << 16);
      pk.w = (r1 + (uint_t)xc0) | ((r1 + (uint_t)xc1) << 16);
      *(uint4*)(wrow + (l * 4 + p) * 4) = pk;
    }
  }
  __syncthreads();

  // ---------- phase 2: lane = (q, h, dg) ----------
  const int h  = (tid >> 2) & 7;
  const int dg = tid & 3;
  const uint_t* wrow = wlds + (size_t)(q * 8 + h) * 68;
  const char* vbyte = (const char*)value + (uint_t)h * 64u + (uint_t)dg * 16u;
  float acc[8] = {};

#define ACCUM8V(U4, WV) {                                                          \
    const uint_t uu0 = (U4).x, uu1 = (U4).y, uu2 = (U4).z, uu3 = (U4).w;           \
    acc[0] = fmaf((WV), h_lo(uu0), acc[0]);                                        \
    acc[1] = fmaf((WV), h_hi(uu0), acc[1]);                                        \
    acc[2] = fmaf((WV), h_lo(uu1), acc[2]);                                        \
    acc[3] = fmaf((WV), h_hi(uu1), acc[3]);                                        \
    acc[4] = fmaf((WV), h_lo(uu2), acc[4]);                                        \
    acc[5] = fmaf((WV), h_hi(uu2), acc[5]);                                        \
    acc[6] = fmaf((WV), h_lo(uu3), acc[6]);                                        \
    acc[7] = fmaf((WV), h_hi(uu3), acc[7]); }

#pragma unroll
  for (int pt = 0; pt < 16; ++pt) {
    const uint4 pk = *(const uint4*)(wrow + pt * 4);
    const float w0 = h_lo(pk.x), w1 = h_hi(pk.x);
    const float w2 = h_lo(pk.y), w3 = h_hi(pk.y);
    const uint_t i0 = pk.z & 0xffffu, i1 = pk.z >> 16;
    const uint_t i2 = pk.w & 0xffffu, i3 = pk.w >> 16;
    { const uint4 g = *(const uint4*)(vbyte + (size_t)i0 * 512u); ACCUM8V(g, w0); }
    { const uint4 g = *(const uint4*)(vbyte + (size_t)i1 * 512u); ACCUM8V(g, w1); }
    { const uint4 g = *(const uint4*)(vbyte + (size_t)i2 * 512u); ACCUM8V(g, w2); }
    { const uint4 g = *(const uint4*)(vbyte + (size_t)i3 * 512u); ACCUM8V(g, w3); }
  }

  // epilogue: single f16 output (no hi|lo), one 16B store
  const uint4 o = make_uint4(pkrtz(acc[0], acc[1]), pkrtz(acc[2], acc[3]),
                             pkrtz(acc[4], acc[5]), pkrtz(acc[6], acc[7]));
  *(uint4*)(samp + (size_t)qg * 256 + h * 32 + dg * 8) = o;
}

extern "C" void kernel_launch(void* const* d_in, const int* in_sizes, int n_in,
                              void* d_out, int out_size, void* d_ws, size_t ws_size,
                              hipStream_t stream) {
  const float* query         = (const float*)d_in[0];
  const float* ref_pts       = (const float*)d_in[1];
  const float* input_flatten = (const float*)d_in[2];
  const int*   sshapes       = (const int*)d_in[3];
  const int*   lstart        = (const int*)d_in[4];
  const float* w_val  = (const float*)d_in[5];
  const float* b_val  = (const float*)d_in[6];
  const float* w_off  = (const float*)d_in[7];
  const float* b_off  = (const float*)d_in[8];
  const float* w_attn = (const float*)d_in[9];
  const float* b_attn = (const float*)d_in[10];
  const float* w_out  = (const float*)d_in[11];
  const float* b_out  = (const float*)d_in[12];
  float* out = (float*)d_out;

  char* ws = (char*)d_ws;
  unsigned short* valb   = (unsigned short*)(ws);                 // 11,141,120  [B,LV,256] f16
  unsigned short* samp   = (unsigned short*)(ws + 11141120);      // 11,141,120  [M,256] f16
  unsigned short* offb   = (unsigned short*)(ws + 22282240);      // 11,141,120  [M,256] f16
  unsigned short* logitb = (unsigned short*)(ws + 33423360);      //  5,570,560  [M,128] f16
  unsigned short* Wcat   = (unsigned short*)(ws + 38993920);      //    196,608  [384][256] f16
  unsigned short* Wo     = (unsigned short*)(ws + 39190528);      //    131,072  [256][256] f16
  unsigned short* Wvt    = (unsigned short*)(ws + 39321600);      //    131,072  [256][256] f16

  dim3 blk(256);
  conv_weights<<<dim3(4, 14), blk, 0, stream>>>(w_off, w_out, w_val, w_attn, Wcat, Wo, Wvt);
  // value + [off|logits] in ONE dispatch (850 blocks), A reg-staged f32->f16
  gemm_front<<<dim3(5, M_TOT / 128), blk, 0, stream>>>(
      input_flatten, query, Wvt, Wcat, b_val, b_off, b_attn, valb, offb, logitb);
  msda_sample_v14<<<dim3(M_TOT / 8), blk, 0, stream>>>(
      offb, logitb, valb, ref_pts, sshapes, lstart, samp);
  // out = samp(f16) @ Wo^T + b_out, K=256
  gemm_out<<<dim3(2, M_TOT / 128), blk, 0, stream>>>(samp, Wo, b_out, out);
}

// Round 16
// 82.435 us; speedup vs baseline: 1.2985x; 1.1073x over previous
//
#include <hip/hip_runtime.h>
#include <hip/hip_fp16.h>
#include <math.h>

#define LQ 5440
#define LV 5440
#define BATCH_ 4
#define M_TOT (BATCH_ * LQ)   // 21760

typedef _Float16 f16x8 __attribute__((ext_vector_type(8)));
typedef float f32x4 __attribute__((ext_vector_type(4)));
typedef unsigned int uint_t;

__device__ __forceinline__ uint_t f2h2(float a, float b) {   // pack 2 f32 -> f16x2 (RNE)
  const unsigned short ua = __half_as_ushort(__float2half(a));
  const unsigned short ub = __half_as_ushort(__float2half(b));
  return (uint_t)ua | ((uint_t)ub << 16);
}
__device__ __forceinline__ uint_t pkrtz(float a, float b) {  // HW packed f32->f16 (RTZ), 1 op
  auto r = __builtin_amdgcn_cvt_pkrtz(a, b);                 // __fp16 ext_vector(2)
  uint_t u;
  __builtin_memcpy(&u, &r, 4);
  return u;
}
__device__ __forceinline__ float h_lo(uint_t u) {
  return __half2float(__ushort_as_half((unsigned short)(u & 0xffffu)));
}
__device__ __forceinline__ float h_hi(uint_t u) {
  return __half2float(__ushort_as_half((unsigned short)(u >> 16)));
}

// ---------------- weight conversion (transpose + f16) ----------------
// Wcat [384][256]: rows 0..255 = w_off^T, rows 256..383 = w_attn^T
// Wo   [256][256]: w_out^T ; Wvt [256][256]: w_val^T   (all f16 RNE)
__global__ __launch_bounds__(256) void conv_weights(
    const float* __restrict__ w_off, const float* __restrict__ w_out,
    const float* __restrict__ w_val, const float* __restrict__ w_attn,
    unsigned short* __restrict__ Wcat, unsigned short* __restrict__ Wo,
    unsigned short* __restrict__ Wvt)
{
  __shared__ float tbuf[64][65];
  const int tid = threadIdx.x;
  const int k0 = blockIdx.x * 64;
  const int yy = blockIdx.y;
  const float* src; unsigned short* dst; int N; int ntile; int roff = 0;
  if (yy < 4)       { src = w_off;  dst = Wcat; N = 256; ntile = yy; }
  else if (yy < 8)  { src = w_out;  dst = Wo;   N = 256; ntile = yy - 4; }
  else if (yy < 12) { src = w_val;  dst = Wvt;  N = 256; ntile = yy - 8; }
  else              { src = w_attn; dst = Wcat; N = 128; ntile = yy - 12; roff = 256; }
  const int n0 = ntile * 64;
#pragma unroll
  for (int i = 0; i < 16; ++i) {
    const int r = (tid >> 6) + i * 4;
    const int c = tid & 63;
    tbuf[r][c] = src[(size_t)(k0 + r) * N + n0 + c];
  }
  __syncthreads();
#pragma unroll
  for (int i = 0; i < 16; ++i) {
    const int n = (tid >> 6) + i * 4;
    const int kk = tid & 63;
    dst[(size_t)(roff + n0 + n) * 256 + k0 + kk] =
        __half_as_ushort(__float2half(tbuf[kk][n]));
  }
}

// ---------------- front GEMM: value + off/logit fused, XCD-grouped grid ----------------
// 1-D grid of 880 blocks: X=P&7 (XCD), j=P>>3; p=j%5 (panel), r=X*22+j/5 (row-block).
// Same-row panels run consecutively on the SAME XCD -> A row-slab is an L2 hit for
// panels 2..5 (was: 5 panels on 5 different XCDs, 5x A re-fetch).
// p<2 -> value panel (A=input_flatten, B=Wvt); p in 2..4 -> fused (A=query, B=Wcat).
__global__ __launch_bounds__(256) void gemm_front(
    const float* __restrict__ ifl, const float* __restrict__ query,
    const unsigned short* __restrict__ Wvt, const unsigned short* __restrict__ Wcat,
    const float* __restrict__ b_val, const float* __restrict__ b_off,
    const float* __restrict__ b_attn,
    unsigned short* __restrict__ valb, unsigned short* __restrict__ offb,
    unsigned short* __restrict__ logitb)
{
  const int P = blockIdx.x;
  const int X = P & 7;
  const int j = P >> 3;
  const int p = j % 5;
  const int rblk = X * 22 + j / 5;
  if (rblk >= M_TOT / 128) return;

  __shared__ unsigned short As[128 * 64];
  __shared__ unsigned short Bs[128 * 64];
  const int tid = threadIdx.x;
  const int w = tid >> 6, lane = tid & 63;
  const int wm = w >> 1, wn = w & 1;
  const int lr = lane & 15, lk = lane >> 4;
  const bool isval = p < 2;
  const float* Af = isval ? ifl : query;
  const unsigned short* Bt = isval ? Wvt : Wcat;
  const int n0 = (isval ? p : p - 2) * 128;
  const int m0 = rblk * 128;

  f32x4 acc[4][4] = {};

  for (int t = 0; t < 4; ++t) {
    const int ka = t * 64;
    // B staging (async) first; A cvt work overlaps it
#pragma unroll
    for (int i = 0; i < 4; ++i) {
      const int rbase = i * 32 + w * 8;
      const int row = rbase + (lane >> 3);
      const int slot = lane & 7;
      const int gs = slot ^ (row & 7);                 // inverse-swizzle SOURCE (rule 21)
      const unsigned short* gp = Bt + (size_t)(n0 + row) * 256 + ka + gs * 8;
      __builtin_amdgcn_global_load_lds(
          (const __attribute__((address_space(1))) uint_t*)gp,
          (__attribute__((address_space(3))) uint_t*)(Bs + rbase * 64), 16, 0, 0);
    }
#pragma unroll
    for (int i = 0; i < 4; ++i) {
      const int rbase = i * 32 + w * 8;
      const int row = rbase + (lane >> 3);
      const int slot = lane & 7;
      const int gs = slot ^ (row & 7);
      const float* gp = Af + (size_t)(m0 + row) * 256 + ka + gs * 8;
      const float4 a0 = *(const float4*)gp;
      const float4 a1 = *(const float4*)(gp + 4);
      *(uint4*)&As[(size_t)row * 64 + slot * 8] =
          make_uint4(pkrtz(a0.x, a0.y), pkrtz(a0.z, a0.w),
                     pkrtz(a1.x, a1.y), pkrtz(a1.z, a1.w));
    }
    asm volatile("s_waitcnt vmcnt(0)" ::: "memory");
    __syncthreads();
#pragma unroll
    for (int kk = 0; kk < 2; ++kk) {
      f16x8 af[4], bfv[4];
#pragma unroll
      for (int m = 0; m < 4; ++m) {
        const int row = wm * 64 + m * 16 + lr;
        const int so = (kk * 4 + lk) ^ (row & 7);      // swizzled read
        af[m] = *(const f16x8*)((const char*)As + row * 128 + so * 16);
      }
#pragma unroll
      for (int n = 0; n < 4; ++n) {
        const int row = wn * 64 + n * 16 + lr;
        const int so = (kk * 4 + lk) ^ (row & 7);
        bfv[n] = *(const f16x8*)((const char*)Bs + row * 128 + so * 16);
      }
#pragma unroll
      for (int m = 0; m < 4; ++m)
#pragma unroll
        for (int n = 0; n < 4; ++n)
          acc[m][n] = __builtin_amdgcn_mfma_f32_16x16x32_f16(af[m], bfv[n], acc[m][n], 0, 0, 0);
    }
    __syncthreads();
  }
#pragma unroll
  for (int n = 0; n < 4; ++n) {
    const int col = n0 + wn * 64 + n * 16 + lr;
    const float bv = isval ? b_val[col] : (col < 256 ? b_off[col] : b_attn[col - 256]);
#pragma unroll
    for (int m = 0; m < 4; ++m) {
      const int rbase = m0 + wm * 64 + m * 16 + lk * 4;
#pragma unroll
      for (int j2 = 0; j2 < 4; ++j2) {
        const float v = acc[m][n][j2] + bv;
        const int row = rbase + j2;
        const unsigned short hv = __half_as_ushort(__float2half(v));
        if (isval)          valb[(size_t)row * 256 + col] = hv;
        else if (col < 256) offb[(size_t)row * 256 + col] = hv;
        else                logitb[(size_t)row * 128 + (col - 256)] = hv;
      }
    }
  }
}

// ---------------- out GEMM: out = samp(f16) @ Wo^T + b_out, K=256, XCD-grouped ----------------
// 1-D grid of 352 blocks: X=P&7, j=P>>3; p=j%2 (N-panel), r=X*22+j/2.
__global__ __launch_bounds__(256) void gemm_out(
    const unsigned short* __restrict__ A,    // samp f16 [M,256]
    const unsigned short* __restrict__ Bt,   // Wo f16 [256][256]
    const float* __restrict__ bias,
    float* __restrict__ C)
{
  const int P = blockIdx.x;
  const int X = P & 7;
  const int j = P >> 3;
  const int p = j % 2;
  const int rblk = X * 22 + j / 2;
  if (rblk >= M_TOT / 128) return;

  __shared__ unsigned short As[128 * 64];
  __shared__ unsigned short Bs[128 * 64];
  const int tid = threadIdx.x;
  const int w = tid >> 6, lane = tid & 63;
  const int wm = w >> 1, wn = w & 1;
  const int lr = lane & 15, lk = lane >> 4;
  const int m0 = rblk * 128, n0 = p * 128;

  f32x4 acc[4][4] = {};

  for (int t = 0; t < 4; ++t) {
    const int ka = t * 64;
#pragma unroll
    for (int i = 0; i < 4; ++i) {
      const int rbase = i * 32 + w * 8;
      const int row = rbase + (lane >> 3);
      const int slot = lane & 7;
      const int gs = slot ^ (row & 7);
      const unsigned short* gp = A + (size_t)(m0 + row) * 256 + ka + gs * 8;
      __builtin_amdgcn_global_load_lds(
          (const __attribute__((address_space(1))) uint_t*)gp,
          (__attribute__((address_space(3))) uint_t*)(As + rbase * 64), 16, 0, 0);
    }
#pragma unroll
    for (int i = 0; i < 4; ++i) {
      const int rbase = i * 32 + w * 8;
      const int row = rbase + (lane >> 3);
      const int slot = lane & 7;
      const int gs = slot ^ (row & 7);
      const unsigned short* gp = Bt + (size_t)(n0 + row) * 256 + ka + gs * 8;
      __builtin_amdgcn_global_load_lds(
          (const __attribute__((address_space(1))) uint_t*)gp,
          (__attribute__((address_space(3))) uint_t*)(Bs + rbase * 64), 16, 0, 0);
    }
    asm volatile("s_waitcnt vmcnt(0)" ::: "memory");
    __syncthreads();
#pragma unroll
    for (int kk = 0; kk < 2; ++kk) {
      f16x8 af[4], bfv[4];
#pragma unroll
      for (int m = 0; m < 4; ++m) {
        const int row = wm * 64 + m * 16 + lr;
        const int so = (kk * 4 + lk) ^ (row & 7);
        af[m] = *(const f16x8*)((const char*)As + row * 128 + so * 16);
      }
#pragma unroll
      for (int n = 0; n < 4; ++n) {
        const int row = wn * 64 + n * 16 + lr;
        const int so = (kk * 4 + lk) ^ (row & 7);
        bfv[n] = *(const f16x8*)((const char*)Bs + row * 128 + so * 16);
      }
#pragma unroll
      for (int m = 0; m < 4; ++m)
#pragma unroll
        for (int n = 0; n < 4; ++n)
          acc[m][n] = __builtin_amdgcn_mfma_f32_16x16x32_f16(af[m], bfv[n], acc[m][n], 0, 0, 0);
    }
    __syncthreads();
  }
#pragma unroll
  for (int n = 0; n < 4; ++n) {
    const int col = n0 + wn * 64 + n * 16 + lr;
    const float bv = bias[col];
#pragma unroll
    for (int m = 0; m < 4; ++m) {
      const int rbase = m0 + wm * 64 + m * 16 + lk * 4;
#pragma unroll
      for (int j2 = 0; j2 < 4; ++j2)
        C[(size_t)(rbase + j2) * 256 + col] = acc[m][n][j2] + bv;
    }
  }
}

// ---------------- sampler v14 (unchanged): two-phase + batch->XCD swizzle, all-f16 ----
// L = ((P&7)>>1)*680 + (P&1)*340 + (P>>3), bijective for P in [0,2720): batch b -> XCDs {2b,2b+1}.
__global__ __launch_bounds__(256) void msda_sample_v14(
    const unsigned short* __restrict__ off_buf,   // [M,256] f16
    const unsigned short* __restrict__ logit_buf, // [M,128] f16
    const unsigned short* __restrict__ value,     // [B,LV,256] f16
    const float* __restrict__ ref_pts,            // [B,LQ,4,2]
    const int*  __restrict__ sshapes, const int* __restrict__ lstart,
    unsigned short* __restrict__ samp)            // [M,256] f16
{
  __shared__ uint_t wlds[64 * 68];                // 17,408 B
  const int tid = threadIdx.x;
  const int P  = blockIdx.x;
  const int L  = (((P & 7) >> 1) * 680) + ((P & 1) * 340) + (P >> 3);
  const int q0 = L * 8;
  const int b  = L / (LQ / 8);
  const int q  = tid >> 5;
  const int qg = q0 + q;

  // ---------- phase 1: lane = (q, h, l) ----------
  {
    const int h  = (tid >> 2) & 7;
    const int l  = tid & 3;
    const int Hl = sshapes[2 * l], Wl = sshapes[2 * l + 1];
    const int st = lstart[l];
    const float rx = ref_pts[(size_t)qg * 8 + l * 2 + 0];
    const float ry = ref_pts[(size_t)qg * 8 + l * 2 + 1];
    const float fx = rx * (float)Wl - 0.5f;
    const float fy = ry * (float)Hl - 0.5f;

    const uint4 og = *(const uint4*)(off_buf + (size_t)qg * 256 + h * 32 + l * 8);
    const float offv[8] = {h_lo(og.x), h_hi(og.x), h_lo(og.y), h_hi(og.y),
                           h_lo(og.z), h_hi(og.z), h_lo(og.w), h_hi(og.w)};

    const uint2 lgu = *(const uint2*)(logit_buf + (size_t)qg * 128 + h * 16 + l * 4);
    float lg[4];
    lg[0] = h_lo(lgu.x); lg[1] = h_hi(lgu.x);
    lg[2] = h_lo(lgu.y); lg[3] = h_hi(lgu.y);

    // cooperative softmax over the 16 logits of (q,h) (4 lanes x 4)
    float mx = fmaxf(fmaxf(lg[0], lg[1]), fmaxf(lg[2], lg[3]));
    mx = fmaxf(mx, __shfl_xor(mx, 1));
    mx = fmaxf(mx, __shfl_xor(mx, 2));
    float ex[4]; float ssum = 0.f;
#pragma unroll
    for (int p = 0; p < 4; ++p) { ex[p] = __expf(lg[p] - mx); ssum += ex[p]; }
    ssum += __shfl_xor(ssum, 1);
    ssum += __shfl_xor(ssum, 2);
    const float inv = 1.f / ssum;

    const uint_t base_idx = (uint_t)b * LV + (uint_t)st;
    uint_t* wrow = wlds + (size_t)(q * 8 + h) * 68;

#pragma unroll
    for (int p = 0; p < 4; ++p) {
      const float x = fx + offv[p * 2 + 0];
      const float y = fy + offv[p * 2 + 1];
      const float aw = ex[p] * inv;
      const float xf = floorf(x), yf = floorf(y);
      const int x0i = (int)xf, y0i = (int)yf;
      const float wx1 = x - xf, wy1 = y - yf;
      const float wx0 = 1.f - wx1, wy0 = 1.f - wy1;
      const int x1i = x0i + 1, y1i = y0i + 1;
      const bool vx0 = (uint_t)x0i < (uint_t)Wl, vx1 = (uint_t)x1i < (uint_t)Wl;
      const bool vy0 = (uint_t)y0i < (uint_t)Hl, vy1 = (uint_t)y1i < (uint_t)Hl;
      const int xc0 = min(max(x0i, 0), Wl - 1), xc1 = min(max(x1i, 0), Wl - 1);
      const int yc0 = min(max(y0i, 0), Hl - 1), yc1 = min(max(y1i, 0), Hl - 1);
      const float awy0 = aw * wy0, awy1 = aw * wy1;
      const float w00 = (vy0 && vx0) ? awy0 * wx0 : 0.f;
      const float w01 = (vy0 && vx1) ? awy0 * wx1 : 0.f;
      const float w10 = (vy1 && vx0) ? awy1 * wx0 : 0.f;
      const float w11 = (vy1 && vx1) ? awy1 * wx1 : 0.f;
      const uint_t r0 = base_idx + (uint_t)(yc0 * Wl), r1 = base_idx + (uint_t)(yc1 * Wl);
      uint4 pk;
      pk.x = f2h2(w00, w01);
      pk.y = f2h2(w10, w11);
      pk.z = (r0 + (uint_t)xc0) | ((r0 + (uint_t)xc1) << 16);
      pk.w = (r1 + (uint_t)xc0) | ((r1 + (uint_t)xc1) << 16);
      *(uint4*)(wrow + (l * 4 + p) * 4) = pk;
    }
  }
  __syncthreads();

  // ---------- phase 2: lane = (q, h, dg) ----------
  const int h  = (tid >> 2) & 7;
  const int dg = tid & 3;
  const uint_t* wrow = wlds + (size_t)(q * 8 + h) * 68;
  const char* vbyte = (const char*)value + (uint_t)h * 64u + (uint_t)dg * 16u;
  float acc[8] = {};

#define ACCUM8V(U4, WV) {                                                          \
    const uint_t uu0 = (U4).x, uu1 = (U4).y, uu2 = (U4).z, uu3 = (U4).w;           \
    acc[0] = fmaf((WV), h_lo(uu0), acc[0]);                                        \
    acc[1] = fmaf((WV), h_hi(uu0), acc[1]);                                        \
    acc[2] = fmaf((WV), h_lo(uu1), acc[2]);                                        \
    acc[3] = fmaf((WV), h_hi(uu1), acc[3]);                                        \
    acc[4] = fmaf((WV), h_lo(uu2), acc[4]);                                        \
    acc[5] = fmaf((WV), h_hi(uu2), acc[5]);                                        \
    acc[6] = fmaf((WV), h_lo(uu3), acc[6]);                                        \
    acc[7] = fmaf((WV), h_hi(uu3), acc[7]); }

#pragma unroll
  for (int pt = 0; pt < 16; ++pt) {
    const uint4 pk = *(const uint4*)(wrow + pt * 4);
    const float w0 = h_lo(pk.x), w1 = h_hi(pk.x);
    const float w2 = h_lo(pk.y), w3 = h_hi(pk.y);
    const uint_t i0 = pk.z & 0xffffu, i1 = pk.z >> 16;
    const uint_t i2 = pk.w & 0xffffu, i3 = pk.w >> 16;
    { const uint4 g = *(const uint4*)(vbyte + (size_t)i0 * 512u); ACCUM8V(g, w0); }
    { const uint4 g = *(const uint4*)(vbyte + (size_t)i1 * 512u); ACCUM8V(g, w1); }
    { const uint4 g = *(const uint4*)(vbyte + (size_t)i2 * 512u); ACCUM8V(g, w2); }
    { const uint4 g = *(const uint4*)(vbyte + (size_t)i3 * 512u); ACCUM8V(g, w3); }
  }

  // epilogue: single f16 output (no hi|lo), one 16B store
  const uint4 o = make_uint4(pkrtz(acc[0], acc[1]), pkrtz(acc[2], acc[3]),
                             pkrtz(acc[4], acc[5]), pkrtz(acc[6], acc[7]));
  *(uint4*)(samp + (size_t)qg * 256 + h * 32 + dg * 8) = o;
}

extern "C" void kernel_launch(void* const* d_in, const int* in_sizes, int n_in,
                              void* d_out, int out_size, void* d_ws, size_t ws_size,
                              hipStream_t stream) {
  const float* query         = (const float*)d_in[0];
  const float* ref_pts       = (const float*)d_in[1];
  const float* input_flatten = (const float*)d_in[2];
  const int*   sshapes       = (const int*)d_in[3];
  const int*   lstart        = (const int*)d_in[4];
  const float* w_val  = (const float*)d_in[5];
  const float* b_val  = (const float*)d_in[6];
  const float* w_off  = (const float*)d_in[7];
  const float* b_off  = (const float*)d_in[8];
  const float* w_attn = (const float*)d_in[9];
  const float* b_attn = (const float*)d_in[10];
  const float* w_out  = (const float*)d_in[11];
  const float* b_out  = (const float*)d_in[12];
  float* out = (float*)d_out;

  char* ws = (char*)d_ws;
  unsigned short* valb   = (unsigned short*)(ws);                 // 11,141,120  [B,LV,256] f16
  unsigned short* samp   = (unsigned short*)(ws + 11141120);      // 11,141,120  [M,256] f16
  unsigned short* offb   = (unsigned short*)(ws + 22282240);      // 11,141,120  [M,256] f16
  unsigned short* logitb = (unsigned short*)(ws + 33423360);      //  5,570,560  [M,128] f16
  unsigned short* Wcat   = (unsigned short*)(ws + 38993920);      //    196,608  [384][256] f16
  unsigned short* Wo     = (unsigned short*)(ws + 39190528);      //    131,072  [256][256] f16
  unsigned short* Wvt    = (unsigned short*)(ws + 39321600);      //    131,072  [256][256] f16

  dim3 blk(256);
  conv_weights<<<dim3(4, 14), blk, 0, stream>>>(w_off, w_out, w_val, w_attn, Wcat, Wo, Wvt);
  // value + [off|logits] in ONE dispatch, XCD-grouped 1-D grid (880 blocks, 30 idle)
  gemm_front<<<dim3(880), blk, 0, stream>>>(
      input_flatten, query, Wvt, Wcat, b_val, b_off, b_attn, valb, offb, logitb);
  msda_sample_v14<<<dim3(M_TOT / 8), blk, 0, stream>>>(
      offb, logitb, valb, ref_pts, sshapes, lstart, samp);
  // out = samp(f16) @ Wo^T + b_out, K=256, XCD-grouped (352 blocks, 12 idle)
  gemm_out<<<dim3(352), blk, 0, stream>>>(samp, Wo, b_out, out);
}